// Round 1
// baseline (1209.069 us; speedup 1.0000x reference)
//
#include <hip/hip_runtime.h>

constexpr int NN = 40000;
constexpr int NE = 640000;
constexpr int DIM = 128;   // input feature dim; h dim = 2*DIM = 256; out dim = 128

// -------------------- kernel 1: w_sum[dst] += ew --------------------
__global__ void wsum_k(const int* __restrict__ dst, const float* __restrict__ ew,
                       float* __restrict__ wsum) {
    int e = blockIdx.x * 256 + threadIdx.x;
    if (e < NE) atomicAdd(&wsum[dst[e]], ew[e]);
}

// ------ kernel 2: agg[dst][:] += (ew/max(wsum,1e-8)) * x[src][:] ------
// 32 threads per edge, each handles one float4 (4 dims).
__global__ void scatter_k(const int* __restrict__ src, const int* __restrict__ dst,
                          const float* __restrict__ ew, const float* __restrict__ wsum,
                          const float* __restrict__ x, float* __restrict__ agg) {
    int tid = blockIdx.x * 256 + threadIdx.x;   // up to 20.48M, fits int
    int e = tid >> 5;
    int p = tid & 31;
    if (e >= NE) return;
    int s = src[e], dn = dst[e];
    float wn = ew[e] / fmaxf(wsum[dn], 1e-8f);
    float4 v = *reinterpret_cast<const float4*>(x + (size_t)s * DIM + p * 4);
    float* o = agg + (size_t)dn * DIM + p * 4;
    atomicAdd(o + 0, wn * v.x);
    atomicAdd(o + 1, wn * v.y);
    atomicAdd(o + 2, wn * v.z);
    atomicAdd(o + 3, wn * v.w);
}

// -------------------- kernel 3: out = [x|agg] @ W^T + b --------------------
// JROWS = W rows staged in LDS per block (64 -> 2 j-half blocks/chunk; 128 -> 1).
// W staged XOR-swizzled (float4 index kk ^ (row&7)) so the per-lane-row
// ds_read_b128 hits all 32 banks (8-phase minimum instead of 64-way conflict).
// h rows staged in LDS; compute-side h reads are wave-uniform broadcasts.
// Each block handles 80 nodes in 5 groups of 16. 500*80 == 40000 exactly.
template <int JROWS>
__global__ __launch_bounds__(256) void gemm_k(const float* __restrict__ x,
                                              const float* __restrict__ agg,
                                              const float* __restrict__ W,
                                              const float* __restrict__ b,
                                              float* __restrict__ out) {
    constexpr int NJ = 128 / JROWS;   // 2 or 1
    constexpr int JT = JROWS / 64;    // 1 or 2 outputs per thread
    __shared__ float4 Wl[JROWS * 64]; // 64KB or 128KB, swizzled
    __shared__ float4 hl[16 * 64];    // 16 nodes x 256 floats = 16KB

    int t = threadIdx.x;
    int bj, nb;
    if (NJ == 2) { bj = blockIdx.x & 1; nb = blockIdx.x >> 1; }
    else         { bj = 0;              nb = blockIdx.x; }
    int base = nb * 80;

    // stage W rows [bj*JROWS, bj*JROWS+JROWS)
    const float4* Wg = reinterpret_cast<const float4*>(W) + (size_t)bj * JROWS * 64;
    #pragma unroll
    for (int i = 0; i < JROWS * 64 / 256; ++i) {
        int f = t + i * 256;          // one wave covers one 64-f4 row
        int r = f >> 6, kk = f & 63;
        Wl[r * 64 + (kk ^ (r & 7))] = Wg[f];
    }

    int jj  = t & 63;
    int wsl = t >> 6;                 // wave slot 0..3 -> node lane
    int sw  = jj & 7;
    float bv[JT];
    #pragma unroll
    for (int q = 0; q < JT; ++q) bv[q] = b[bj * JROWS + jj + q * 64];

    const float4* xg = reinterpret_cast<const float4*>(x);
    const float4* ag = reinterpret_cast<const float4*>(agg);

    for (int g = 0; g < 5; ++g) {
        int nbase = base + g * 16;
        __syncthreads();              // protect hl from previous iteration
        #pragma unroll
        for (int i = 0; i < 4; ++i) { // stage 16 nodes x 64 f4
            int f = t + i * 256;
            int ln = f >> 6, kk = f & 63;
            size_t node = (size_t)(nbase + ln);
            float4 v = (kk < 32) ? xg[node * 32 + kk] : ag[node * 32 + (kk - 32)];
            hl[ln * 64 + kk] = v;
        }
        __syncthreads();

        float acc[JT][4];
        #pragma unroll
        for (int q = 0; q < JT; ++q)
            #pragma unroll
            for (int n = 0; n < 4; ++n) acc[q][n] = 0.f;

        #pragma unroll 4
        for (int kk = 0; kk < 64; ++kk) {
            float4 h[4];
            #pragma unroll
            for (int n = 0; n < 4; ++n) h[n] = hl[(wsl + 4 * n) * 64 + kk];
            #pragma unroll
            for (int q = 0; q < JT; ++q) {
                float4 w = Wl[(jj + q * 64) * 64 + (kk ^ sw)];
                #pragma unroll
                for (int n = 0; n < 4; ++n)
                    acc[q][n] += w.x * h[n].x + w.y * h[n].y + w.z * h[n].z + w.w * h[n].w;
            }
        }

        #pragma unroll
        for (int q = 0; q < JT; ++q)
            #pragma unroll
            for (int n = 0; n < 4; ++n)
                out[(size_t)(nbase + wsl + 4 * n) * 128 + bj * JROWS + jj + q * 64] =
                    acc[q][n] + bv[q];
    }
}

extern "C" void kernel_launch(void* const* d_in, const int* in_sizes, int n_in,
                              void* d_out, int out_size, void* d_ws, size_t ws_size,
                              hipStream_t stream) {
    const float* x  = (const float*)d_in[0];
    const int*   ei = (const int*)d_in[1];
    const float* ew = (const float*)d_in[2];
    const float* W  = (const float*)d_in[3];
    const float* b  = (const float*)d_in[4];
    float* out = (float*)d_out;
    const int* src = ei;
    const int* dst = ei + NE;

    float* wsum = (float*)d_ws;
    const size_t aggoff = 256 * 1024;
    const size_t aggbytes = (size_t)NN * DIM * 4;
    bool ws_agg = ws_size >= aggoff + aggbytes;
    float* agg = ws_agg ? (float*)((char*)d_ws + aggoff) : out;

    hipMemsetAsync(wsum, 0, NN * 4, stream);
    hipMemsetAsync(agg, 0, aggbytes, stream);

    wsum_k<<<(NE + 255) / 256, 256, 0, stream>>>(dst, ew, wsum);
    scatter_k<<<NE * 32 / 256, 256, 0, stream>>>(src, dst, ew, wsum, x, agg);

    if (ws_agg) {
        gemm_k<64><<<1000, 256, 0, stream>>>(x, agg, W, b, out);   // 500 chunks x 2 j-halves
    } else {
        gemm_k<128><<<500, 256, 0, stream>>>(x, agg, W, b, out);   // agg aliases out: single block per chunk
    }
}

// Round 2
// 287.751 us; speedup vs baseline: 4.2018x; 4.2018x over previous
//
#include <hip/hip_runtime.h>

constexpr int NN = 40000;
constexpr int NE = 640000;
constexpr int DIM = 128;   // input feature dim; h dim = 2*DIM = 256; out dim = 128

// ==================== CSR-build path (no f32 atomics) ====================

// histogram of destination nodes
__global__ void hist_k(const int* __restrict__ dst, int* __restrict__ cnt) {
    int e = blockIdx.x * 256 + threadIdx.x;
    if (e < NE) atomicAdd(&cnt[dst[e]], 1);
}

// single-block exclusive scan over 40000 counts -> ptr[40001], pos[40000]
__global__ __launch_bounds__(1024) void scan_k(const int* __restrict__ cnt,
                                               int* __restrict__ ptr,
                                               int* __restrict__ pos) {
    __shared__ int part[1024];
    int t = threadIdx.x;
    int base_idx = t * 40;          // 1024*40 = 40960 >= 40000
    int loc[40];
    int s = 0;
    #pragma unroll
    for (int i = 0; i < 40; ++i) {
        int idx = base_idx + i;
        int c = (idx < NN) ? cnt[idx] : 0;
        loc[i] = s;
        s += c;
    }
    part[t] = s;
    __syncthreads();
    for (int off = 1; off < 1024; off <<= 1) {
        int v = (t >= off) ? part[t - off] : 0;
        __syncthreads();
        part[t] += v;
        __syncthreads();
    }
    int basep = (t == 0) ? 0 : part[t - 1];
    #pragma unroll
    for (int i = 0; i < 40; ++i) {
        int idx = base_idx + i;
        if (idx < NN) {
            int v = basep + loc[i];
            ptr[idx] = v;
            pos[idx] = v;
        }
    }
    if (t == 1023) ptr[NN] = part[1023];
}

// scatter edge ids into dst-grouped order (int atomics only)
__global__ void order_k(const int* __restrict__ dst, int* __restrict__ pos,
                        int* __restrict__ order) {
    int e = blockIdx.x * 256 + threadIdx.x;
    if (e < NE) {
        int p = atomicAdd(&pos[dst[e]], 1);
        order[p] = e;
    }
}

// gather aggregation: half-wave (32 lanes x float4) per node.
// agg[n] = (sum_e ew*x[src]) / clip(sum_e ew, 1e-8)  == reference math
__global__ __launch_bounds__(256) void aggregate_k(const int* __restrict__ src,
                                                   const float* __restrict__ ew,
                                                   const float* __restrict__ x,
                                                   const int* __restrict__ ptr,
                                                   const int* __restrict__ order,
                                                   float* __restrict__ agg) {
    int wid  = blockIdx.x * 4 + (threadIdx.x >> 6);   // global wave 0..19999
    int half = (threadIdx.x >> 5) & 1;
    int lane = threadIdx.x & 31;
    int n = wid * 2 + half;
    if (n >= NN) return;
    int beg = ptr[n], end = ptr[n + 1];
    const float4* xg = reinterpret_cast<const float4*>(x);
    float4 acc = make_float4(0.f, 0.f, 0.f, 0.f);
    float ws = 0.f;
    for (int e = beg; e < end; ++e) {
        int eid = order[e];          // broadcast within half-wave
        int s   = src[eid];
        float w = ew[eid];
        ws += w;
        float4 v = xg[(size_t)s * 32 + lane];
        acc.x += w * v.x; acc.y += w * v.y; acc.z += w * v.z; acc.w += w * v.w;
    }
    float inv = 1.f / fmaxf(ws, 1e-8f);
    acc.x *= inv; acc.y *= inv; acc.z *= inv; acc.w *= inv;
    reinterpret_cast<float4*>(agg)[(size_t)n * 32 + lane] = acc;
}

// ==================== fallback path (small ws): old atomic scatter ====================

__global__ void wsum_k(const int* __restrict__ dst, const float* __restrict__ ew,
                       float* __restrict__ wsum) {
    int e = blockIdx.x * 256 + threadIdx.x;
    if (e < NE) atomicAdd(&wsum[dst[e]], ew[e]);
}

__global__ void scatter_k(const int* __restrict__ src, const int* __restrict__ dst,
                          const float* __restrict__ ew, const float* __restrict__ wsum,
                          const float* __restrict__ x, float* __restrict__ agg) {
    int tid = blockIdx.x * 256 + threadIdx.x;
    int e = tid >> 5;
    int p = tid & 31;
    if (e >= NE) return;
    int s = src[e], dn = dst[e];
    float wn = ew[e] / fmaxf(wsum[dn], 1e-8f);
    float4 v = *reinterpret_cast<const float4*>(x + (size_t)s * DIM + p * 4);
    float* o = agg + (size_t)dn * DIM + p * 4;
    atomicAdd(o + 0, wn * v.x);
    atomicAdd(o + 1, wn * v.y);
    atomicAdd(o + 2, wn * v.z);
    atomicAdd(o + 3, wn * v.w);
}

// ==================== GEMM: out = [x|agg] @ W^T + b ====================
template <int JROWS>
__global__ __launch_bounds__(256) void gemm_k(const float* __restrict__ x,
                                              const float* __restrict__ agg,
                                              const float* __restrict__ W,
                                              const float* __restrict__ b,
                                              float* __restrict__ out) {
    constexpr int NJ = 128 / JROWS;
    constexpr int JT = JROWS / 64;
    __shared__ float4 Wl[JROWS * 64];
    __shared__ float4 hl[16 * 64];

    int t = threadIdx.x;
    int bj, nb;
    if (NJ == 2) { bj = blockIdx.x & 1; nb = blockIdx.x >> 1; }
    else         { bj = 0;              nb = blockIdx.x; }
    int base = nb * 80;

    const float4* Wg = reinterpret_cast<const float4*>(W) + (size_t)bj * JROWS * 64;
    #pragma unroll
    for (int i = 0; i < JROWS * 64 / 256; ++i) {
        int f = t + i * 256;
        int r = f >> 6, kk = f & 63;
        Wl[r * 64 + (kk ^ (r & 7))] = Wg[f];
    }

    int jj  = t & 63;
    int wsl = t >> 6;
    int sw  = jj & 7;
    float bv[JT];
    #pragma unroll
    for (int q = 0; q < JT; ++q) bv[q] = b[bj * JROWS + jj + q * 64];

    const float4* xg = reinterpret_cast<const float4*>(x);
    const float4* ag = reinterpret_cast<const float4*>(agg);

    for (int g = 0; g < 5; ++g) {
        int nbase = base + g * 16;
        __syncthreads();
        #pragma unroll
        for (int i = 0; i < 4; ++i) {
            int f = t + i * 256;
            int ln = f >> 6, kk = f & 63;
            size_t node = (size_t)(nbase + ln);
            float4 v = (kk < 32) ? xg[node * 32 + kk] : ag[node * 32 + (kk - 32)];
            hl[ln * 64 + kk] = v;
        }
        __syncthreads();

        float acc[JT][4];
        #pragma unroll
        for (int q = 0; q < JT; ++q)
            #pragma unroll
            for (int n = 0; n < 4; ++n) acc[q][n] = 0.f;

        #pragma unroll 4
        for (int kk = 0; kk < 64; ++kk) {
            float4 h[4];
            #pragma unroll
            for (int n = 0; n < 4; ++n) h[n] = hl[(wsl + 4 * n) * 64 + kk];
            #pragma unroll
            for (int q = 0; q < JT; ++q) {
                float4 w = Wl[(jj + q * 64) * 64 + (kk ^ sw)];
                #pragma unroll
                for (int n = 0; n < 4; ++n)
                    acc[q][n] += w.x * h[n].x + w.y * h[n].y + w.z * h[n].z + w.w * h[n].w;
            }
        }

        #pragma unroll
        for (int q = 0; q < JT; ++q)
            #pragma unroll
            for (int n = 0; n < 4; ++n)
                out[(size_t)(nbase + wsl + 4 * n) * 128 + bj * JROWS + jj + q * 64] =
                    acc[q][n] + bv[q];
    }
}

extern "C" void kernel_launch(void* const* d_in, const int* in_sizes, int n_in,
                              void* d_out, int out_size, void* d_ws, size_t ws_size,
                              hipStream_t stream) {
    const float* x  = (const float*)d_in[0];
    const int*   ei = (const int*)d_in[1];
    const float* ew = (const float*)d_in[2];
    const float* W  = (const float*)d_in[3];
    const float* b  = (const float*)d_in[4];
    float* out = (float*)d_out;
    const int* src = ei;
    const int* dst = ei + NE;

    // ws layout (CSR path):
    //   [0, 160000)          cnt -> pos
    //   [256K, 256K+160004)  ptr[40001]
    //   [512K, 512K+2.56M)   order[640000]
    //   [3.5M, 3.5M+20.48M)  agg
    const size_t off_pos   = 0;
    const size_t off_ptr   = 256 * 1024;
    const size_t off_order = 512 * 1024;
    const size_t off_agg   = 3584 * 1024;
    const size_t need = off_agg + (size_t)NN * DIM * 4;

    if (ws_size >= need) {
        int*   pos   = (int*)((char*)d_ws + off_pos);
        int*   ptr   = (int*)((char*)d_ws + off_ptr);
        int*   order = (int*)((char*)d_ws + off_order);
        float* agg   = (float*)((char*)d_ws + off_agg);

        hipMemsetAsync(pos, 0, NN * 4, stream);
        hist_k <<<(NE + 255) / 256, 256, 0, stream>>>(dst, pos);
        scan_k <<<1, 1024, 0, stream>>>(pos, ptr, pos);
        order_k<<<(NE + 255) / 256, 256, 0, stream>>>(dst, pos, order);
        aggregate_k<<<5000, 256, 0, stream>>>(src, ew, x, ptr, order, agg);
        gemm_k<64><<<1000, 256, 0, stream>>>(x, agg, W, b, out);
    } else {
        // fallback: atomic scatter, agg aliases out
        float* wsum = (float*)d_ws;
        float* agg  = out;
        hipMemsetAsync(wsum, 0, NN * 4, stream);
        hipMemsetAsync(agg, 0, (size_t)NN * DIM * 4, stream);
        wsum_k   <<<(NE + 255) / 256, 256, 0, stream>>>(dst, ew, wsum);
        scatter_k<<<NE * 32 / 256, 256, 0, stream>>>(src, dst, ew, wsum, x, agg);
        gemm_k<128><<<500, 256, 0, stream>>>(x, agg, W, b, out);
    }
}

// Round 3
// 158.233 us; speedup vs baseline: 7.6411x; 1.8185x over previous
//
#include <hip/hip_runtime.h>

constexpr int NN = 40000;
constexpr int NE = 640000;
constexpr int DIM = 128;   // h dim = 256; out dim = 128

typedef __attribute__((ext_vector_type(8))) short short8;
typedef __attribute__((ext_vector_type(4))) float f32x4;

// f32 -> bf16 round-to-nearest-even
__device__ __forceinline__ unsigned short rneb(float f) {
    unsigned u = __float_as_uint(f);
    u = (u + 0x7FFFu + ((u >> 16) & 1u)) >> 16;
    return (unsigned short)u;
}
__device__ __forceinline__ float b2f(unsigned short s) {
    return __uint_as_float(((unsigned)s) << 16);
}

// ---------- convert x[40000][128] f32 -> hb[:, 0:128] bf16 ----------
__global__ void cvtx_k(const float* __restrict__ x, unsigned short* __restrict__ hb) {
    int g = blockIdx.x * 256 + threadIdx.x;        // float4-group id
    if (g >= NN * 32) return;
    int row = g >> 5, c4 = g & 31;
    float4 v = reinterpret_cast<const float4*>(x)[g];
    ushort4 o = { rneb(v.x), rneb(v.y), rneb(v.z), rneb(v.w) };
    *reinterpret_cast<ushort4*>(hb + (size_t)row * 256 + c4 * 4) = o;
}

// ---------- convert W[128][256] f32 -> Wb bf16 ----------
__global__ void cvtw_k(const float* __restrict__ W, unsigned short* __restrict__ Wb) {
    int g = blockIdx.x * 256 + threadIdx.x;        // float4-group id
    if (g >= 128 * 64) return;
    float4 v = reinterpret_cast<const float4*>(W)[g];
    ushort4 o = { rneb(v.x), rneb(v.y), rneb(v.z), rneb(v.w) };
    reinterpret_cast<ushort4*>(Wb)[g] = o;
}

// ---------- histogram of dst ----------
__global__ void hist_k(const int* __restrict__ dst, int* __restrict__ cnt) {
    int e = blockIdx.x * 256 + threadIdx.x;
    if (e < NE) atomicAdd(&cnt[dst[e]], 1);
}

// ---------- hierarchical exclusive scan: 40 blocks x 1000 ----------
__global__ __launch_bounds__(256) void bsum_k(const int* __restrict__ cnt,
                                              int* __restrict__ bsum) {
    int j = blockIdx.x, t = threadIdx.x;
    int s = 0;
    #pragma unroll
    for (int i = 0; i < 4; ++i) {
        int o = t + i * 256;
        if (o < 1000) s += cnt[j * 1000 + o];
    }
    #pragma unroll
    for (int o = 32; o; o >>= 1) s += __shfl_down(s, o);
    __shared__ int wsh[4];
    if ((t & 63) == 0) wsh[t >> 6] = s;
    __syncthreads();
    if (t == 0) bsum[j] = wsh[0] + wsh[1] + wsh[2] + wsh[3];
}

__global__ void scan2_k(const int* __restrict__ bsum, int* __restrict__ boff,
                        int* __restrict__ ptr) {
    int t = threadIdx.x;                           // 64 threads
    int own = (t < 40) ? bsum[t] : 0;
    int v = own;
    #pragma unroll
    for (int o = 1; o < 64; o <<= 1) {
        int u = __shfl_up(v, o);
        if (t >= o) v += u;
    }
    if (t < 40) boff[t] = v - own;
    if (t == 39) ptr[NN] = v;
}

__global__ __launch_bounds__(1024) void scan3_k(const int* __restrict__ boff,
                                                int* __restrict__ poscnt,   // cnt in, pos out
                                                int* __restrict__ ptr) {
    __shared__ int sc[1024];
    int t = threadIdx.x;
    int idx = blockIdx.x * 1000 + t;
    int c = (t < 1000) ? poscnt[idx] : 0;
    sc[t] = c;
    __syncthreads();
    for (int o = 1; o < 1024; o <<= 1) {
        int u = (t >= o) ? sc[t - o] : 0;
        __syncthreads();
        sc[t] += u;
        __syncthreads();
    }
    if (t < 1000) {
        int excl = sc[t] - c + boff[blockIdx.x];
        ptr[idx] = excl;
        poscnt[idx] = excl;
    }
}

// ---------- scatter edge ids into dst-grouped order ----------
__global__ void order_k(const int* __restrict__ dst, int* __restrict__ pos,
                        int* __restrict__ order) {
    int e = blockIdx.x * 256 + threadIdx.x;
    if (e < NE) {
        int p = atomicAdd(&pos[dst[e]], 1);
        order[p] = e;
    }
}

// ---------- gather aggregation: one wave per node, bf16 rows ----------
// writes agg (bf16) into hb[:, 128:256]
__global__ __launch_bounds__(256) void aggregate_k(const int* __restrict__ src,
                                                   const float* __restrict__ ew,
                                                   const int* __restrict__ ptr,
                                                   const int* __restrict__ order,
                                                   unsigned short* __restrict__ hb) {
    int n = blockIdx.x * 4 + (threadIdx.x >> 6);
    int lane = threadIdx.x & 63;
    const ushort2* hb2 = reinterpret_cast<const ushort2*>(hb);   // row stride 128
    int beg = ptr[n], end = ptr[n + 1];
    float ax = 0.f, ay = 0.f, ws = 0.f;
    int e = beg;
    for (; e + 4 <= end; e += 4) {
        int i0 = order[e], i1 = order[e + 1], i2 = order[e + 2], i3 = order[e + 3];
        int s0 = src[i0], s1 = src[i1], s2 = src[i2], s3 = src[i3];
        float w0 = ew[i0], w1 = ew[i1], w2 = ew[i2], w3 = ew[i3];
        ushort2 v0 = hb2[(size_t)s0 * 128 + lane];
        ushort2 v1 = hb2[(size_t)s1 * 128 + lane];
        ushort2 v2 = hb2[(size_t)s2 * 128 + lane];
        ushort2 v3 = hb2[(size_t)s3 * 128 + lane];
        ax += w0 * b2f(v0.x) + w1 * b2f(v1.x) + w2 * b2f(v2.x) + w3 * b2f(v3.x);
        ay += w0 * b2f(v0.y) + w1 * b2f(v1.y) + w2 * b2f(v2.y) + w3 * b2f(v3.y);
        ws += w0 + w1 + w2 + w3;
    }
    for (; e < end; ++e) {
        int i0 = order[e];
        int s0 = src[i0];
        float w0 = ew[i0];
        ushort2 v0 = hb2[(size_t)s0 * 128 + lane];
        ax += w0 * b2f(v0.x);
        ay += w0 * b2f(v0.y);
        ws += w0;
    }
    float inv = 1.f / fmaxf(ws, 1e-8f);
    ushort2 o = { rneb(ax * inv), rneb(ay * inv) };
    reinterpret_cast<ushort2*>(hb)[(size_t)n * 128 + 64 + lane] = o;
}

// ---------- MFMA GEMM, zero-LDS: out = hb @ Wb^T + b ----------
// m92/m97 fragment recipe: A and Bt both [row][K]; lane l reads 8 consecutive
// bf16 at row=(l&15), k=(l>>4)*8; D: col=l&15, row=(l>>4)*4+reg.
__global__ __launch_bounds__(256) void gemm_mfma_k(const unsigned short* __restrict__ hb,
                                                   const unsigned short* __restrict__ Wb,
                                                   const float* __restrict__ b,
                                                   float* __restrict__ out) {
    int w = threadIdx.x >> 6, l = threadIdx.x & 63;
    int l15 = l & 15, lg = l >> 4;
    int rb = blockIdx.x * 128 + w * 32;         // wave's 32-row slab

    f32x4 acc[2][8];
    #pragma unroll
    for (int i = 0; i < 2; ++i)
        #pragma unroll
        for (int c = 0; c < 8; ++c) acc[i][c] = (f32x4)0.f;

    float bias[8];
    #pragma unroll
    for (int c = 0; c < 8; ++c) bias[c] = b[c * 16 + l15];

    int r0 = rb + l15;      if (r0 > NN - 1) r0 = NN - 1;
    int r1 = rb + 16 + l15; if (r1 > NN - 1) r1 = NN - 1;

    #pragma unroll
    for (int step = 0; step < 8; ++step) {
        int kg = step * 32 + lg * 8;
        short8 a0 = *reinterpret_cast<const short8*>(hb + (size_t)r0 * 256 + kg);
        short8 a1 = *reinterpret_cast<const short8*>(hb + (size_t)r1 * 256 + kg);
        #pragma unroll
        for (int c = 0; c < 8; ++c) {
            short8 bf = *reinterpret_cast<const short8*>(Wb + (size_t)(c * 16 + l15) * 256 + kg);
            acc[0][c] = __builtin_amdgcn_mfma_f32_16x16x32_bf16(a0, bf, acc[0][c], 0, 0, 0);
            acc[1][c] = __builtin_amdgcn_mfma_f32_16x16x32_bf16(a1, bf, acc[1][c], 0, 0, 0);
        }
    }

    #pragma unroll
    for (int i = 0; i < 2; ++i) {
        int rbase = rb + i * 16 + lg * 4;
        #pragma unroll
        for (int c = 0; c < 8; ++c) {
            #pragma unroll
            for (int r = 0; r < 4; ++r) {
                int row = rbase + r;
                if (row < NN)
                    out[(size_t)row * 128 + c * 16 + l15] = acc[i][c][r] + bias[c];
            }
        }
    }
}

// ==================== fallback path (small ws): atomic scatter + f32 GEMM ====================

__global__ void wsum_k(const int* __restrict__ dst, const float* __restrict__ ew,
                       float* __restrict__ wsum) {
    int e = blockIdx.x * 256 + threadIdx.x;
    if (e < NE) atomicAdd(&wsum[dst[e]], ew[e]);
}

__global__ void scatter_k(const int* __restrict__ src, const int* __restrict__ dst,
                          const float* __restrict__ ew, const float* __restrict__ wsum,
                          const float* __restrict__ x, float* __restrict__ agg) {
    int tid = blockIdx.x * 256 + threadIdx.x;
    int e = tid >> 5;
    int p = tid & 31;
    if (e >= NE) return;
    int s = src[e], dn = dst[e];
    float wn = ew[e] / fmaxf(wsum[dn], 1e-8f);
    float4 v = *reinterpret_cast<const float4*>(x + (size_t)s * DIM + p * 4);
    float* o = agg + (size_t)dn * DIM + p * 4;
    atomicAdd(o + 0, wn * v.x);
    atomicAdd(o + 1, wn * v.y);
    atomicAdd(o + 2, wn * v.z);
    atomicAdd(o + 3, wn * v.w);
}

__global__ __launch_bounds__(256) void gemm_f32_k(const float* __restrict__ x,
                                                  const float* __restrict__ agg,
                                                  const float* __restrict__ W,
                                                  const float* __restrict__ b,
                                                  float* __restrict__ out) {
    __shared__ float4 Wl[128 * 64];
    __shared__ float4 hl[16 * 64];
    int t = threadIdx.x;
    int base = blockIdx.x * 80;
    const float4* Wg = reinterpret_cast<const float4*>(W);
    #pragma unroll
    for (int i = 0; i < 32; ++i) {
        int f = t + i * 256;
        int r = f >> 6, kk = f & 63;
        Wl[r * 64 + (kk ^ (r & 7))] = Wg[f];
    }
    int jj = t & 63, wsl = t >> 6, sw = jj & 7;
    float bv[2] = { b[jj], b[jj + 64] };
    const float4* xg = reinterpret_cast<const float4*>(x);
    const float4* ag = reinterpret_cast<const float4*>(agg);
    for (int g = 0; g < 5; ++g) {
        int nbase = base + g * 16;
        __syncthreads();
        #pragma unroll
        for (int i = 0; i < 4; ++i) {
            int f = t + i * 256;
            int ln = f >> 6, kk = f & 63;
            size_t node = (size_t)(nbase + ln);
            hl[ln * 64 + kk] = (kk < 32) ? xg[node * 32 + kk] : ag[node * 32 + (kk - 32)];
        }
        __syncthreads();
        float acc[2][4];
        #pragma unroll
        for (int q = 0; q < 2; ++q)
            #pragma unroll
            for (int n = 0; n < 4; ++n) acc[q][n] = 0.f;
        #pragma unroll 4
        for (int kk = 0; kk < 64; ++kk) {
            float4 h[4];
            #pragma unroll
            for (int n = 0; n < 4; ++n) h[n] = hl[(wsl + 4 * n) * 64 + kk];
            #pragma unroll
            for (int q = 0; q < 2; ++q) {
                float4 wv = Wl[(jj + q * 64) * 64 + (kk ^ sw)];
                #pragma unroll
                for (int n = 0; n < 4; ++n)
                    acc[q][n] += wv.x * h[n].x + wv.y * h[n].y + wv.z * h[n].z + wv.w * h[n].w;
            }
        }
        #pragma unroll
        for (int q = 0; q < 2; ++q)
            #pragma unroll
            for (int n = 0; n < 4; ++n)
                out[(size_t)(nbase + wsl + 4 * n) * 128 + jj + q * 64] = acc[q][n] + bv[q];
    }
}

extern "C" void kernel_launch(void* const* d_in, const int* in_sizes, int n_in,
                              void* d_out, int out_size, void* d_ws, size_t ws_size,
                              hipStream_t stream) {
    const float* x  = (const float*)d_in[0];
    const int*   ei = (const int*)d_in[1];
    const float* ew = (const float*)d_in[2];
    const float* W  = (const float*)d_in[3];
    const float* b  = (const float*)d_in[4];
    float* out = (float*)d_out;
    const int* src = ei;
    const int* dst = ei + NE;

    // ws layout (bytes):
    //   0        : pos/cnt [40000 int] (160000)   -- dead after order_k, reused for Wb (64 KB)
    //   163840   : ptr [40001 int]
    //   327680   : bsum [40 int]
    //   328192   : boff [40 int]
    //   331776   : order [640000 int] (2.56 MB)
    //   2893824  : hb [40000][256] bf16 (20.48 MB)
    const size_t off_ptr   = 163840;
    const size_t off_bsum  = 327680;
    const size_t off_boff  = 328192;
    const size_t off_order = 331776;
    const size_t off_hb    = 2893824;
    const size_t need = off_hb + (size_t)NN * 256 * 2;

    if (ws_size >= need) {
        int* pos   = (int*)d_ws;
        int* ptr   = (int*)((char*)d_ws + off_ptr);
        int* bsum  = (int*)((char*)d_ws + off_bsum);
        int* boff  = (int*)((char*)d_ws + off_boff);
        int* order = (int*)((char*)d_ws + off_order);
        unsigned short* hb = (unsigned short*)((char*)d_ws + off_hb);
        unsigned short* Wb = (unsigned short*)d_ws;          // overlays pos after order_k

        hipMemsetAsync(pos, 0, NN * 4, stream);
        cvtx_k <<<NN * 32 / 256, 256, 0, stream>>>(x, hb);
        hist_k <<<(NE + 255) / 256, 256, 0, stream>>>(dst, pos);
        bsum_k <<<40, 256, 0, stream>>>(pos, bsum);
        scan2_k<<<1, 64, 0, stream>>>(bsum, boff, ptr);
        scan3_k<<<40, 1024, 0, stream>>>(boff, pos, ptr);
        order_k<<<(NE + 255) / 256, 256, 0, stream>>>(dst, pos, order);
        cvtw_k <<<32, 256, 0, stream>>>(W, Wb);
        aggregate_k<<<NN / 4, 256, 0, stream>>>(src, ew, ptr, order, hb);
        gemm_mfma_k<<<(NN + 127) / 128, 256, 0, stream>>>(hb, Wb, b, out);
    } else {
        float* wsum = (float*)d_ws;
        float* agg  = out;
        hipMemsetAsync(wsum, 0, NN * 4, stream);
        hipMemsetAsync(agg, 0, (size_t)NN * DIM * 4, stream);
        wsum_k   <<<(NE + 255) / 256, 256, 0, stream>>>(dst, ew, wsum);
        scatter_k<<<NE * 32 / 256, 256, 0, stream>>>(src, dst, ew, wsum, x, agg);
        gemm_f32_k<<<500, 256, 0, stream>>>(x, agg, W, b, out);
    }
}

// Round 4
// 136.416 us; speedup vs baseline: 8.8631x; 1.1599x over previous
//
#include <hip/hip_runtime.h>

constexpr int NN = 40000;
constexpr int NE = 640000;
constexpr int DIM = 128;   // h dim = 256; out dim = 128

typedef __attribute__((ext_vector_type(8))) short short8;
typedef __attribute__((ext_vector_type(4))) float f32x4;

// f32 -> bf16 round-to-nearest-even
__device__ __forceinline__ unsigned short rneb(float f) {
    unsigned u = __float_as_uint(f);
    u = (u + 0x7FFFu + ((u >> 16) & 1u)) >> 16;
    return (unsigned short)u;
}
__device__ __forceinline__ float b2f(unsigned short s) {
    return __uint_as_float(((unsigned)s) << 16);
}

// ---------- fused: x f32 -> hb[:,0:128] bf16  +  dst histogram ----------
__global__ __launch_bounds__(256) void prep_k(const float* __restrict__ x,
                                              unsigned short* __restrict__ hb,
                                              const int* __restrict__ dst,
                                              int* __restrict__ cnt) {
    int bid = blockIdx.x, t = threadIdx.x;
    if (bid < 5000) {                       // 5000*256 == NN*32 float4-groups
        int g = bid * 256 + t;
        int row = g >> 5, c4 = g & 31;
        float4 v = reinterpret_cast<const float4*>(x)[g];
        ushort4 o = { rneb(v.x), rneb(v.y), rneb(v.z), rneb(v.w) };
        *reinterpret_cast<ushort4*>(hb + (size_t)row * 256 + c4 * 4) = o;
    } else {                                // 2500*256 == NE edges
        int e = (bid - 5000) * 256 + t;
        atomicAdd(&cnt[dst[e]], 1);
    }
}

// ---------- convert W[128][256] f32 -> Wb bf16 (after order_k; overlays pos) ----------
__global__ void cvtw_k(const float* __restrict__ W, unsigned short* __restrict__ Wb) {
    int g = blockIdx.x * 256 + threadIdx.x;
    if (g >= 128 * 64) return;
    float4 v = reinterpret_cast<const float4*>(W)[g];
    ushort4 o = { rneb(v.x), rneb(v.y), rneb(v.z), rneb(v.w) };
    reinterpret_cast<ushort4*>(Wb)[g] = o;
}

// ---------- hierarchical exclusive scan: 40 blocks x 1000 ----------
__global__ __launch_bounds__(256) void bsum_k(const int* __restrict__ cnt,
                                              int* __restrict__ bsum) {
    int j = blockIdx.x, t = threadIdx.x;
    int s = 0;
    #pragma unroll
    for (int i = 0; i < 4; ++i) {
        int o = t + i * 256;
        if (o < 1000) s += cnt[j * 1000 + o];
    }
    #pragma unroll
    for (int o = 32; o; o >>= 1) s += __shfl_down(s, o);
    __shared__ int wsh[4];
    if ((t & 63) == 0) wsh[t >> 6] = s;
    __syncthreads();
    if (t == 0) bsum[j] = wsh[0] + wsh[1] + wsh[2] + wsh[3];
}

__global__ void scan2_k(const int* __restrict__ bsum, int* __restrict__ boff,
                        int* __restrict__ ptr) {
    int t = threadIdx.x;                    // 64 threads
    int own = (t < 40) ? bsum[t] : 0;
    int v = own;
    #pragma unroll
    for (int o = 1; o < 64; o <<= 1) {
        int u = __shfl_up(v, o);
        if (t >= o) v += u;
    }
    if (t < 40) boff[t] = v - own;
    if (t == 39) ptr[NN] = v;
}

__global__ __launch_bounds__(1024) void scan3_k(const int* __restrict__ boff,
                                                int* __restrict__ poscnt,   // cnt in, pos out
                                                int* __restrict__ ptr) {
    __shared__ int sc[1024];
    int t = threadIdx.x;
    int idx = blockIdx.x * 1000 + t;
    int c = (t < 1000) ? poscnt[idx] : 0;
    sc[t] = c;
    __syncthreads();
    for (int o = 1; o < 1024; o <<= 1) {
        int u = (t >= o) ? sc[t - o] : 0;
        __syncthreads();
        sc[t] += u;
        __syncthreads();
    }
    if (t < 1000) {
        int excl = sc[t] - c + boff[blockIdx.x];
        ptr[idx] = excl;
        poscnt[idx] = excl;
    }
}

// ---------- scatter packed (src:u16, ew:f16) into dst-grouped order ----------
__global__ void order_k(const int* __restrict__ dst, const int* __restrict__ srcv,
                        const float* __restrict__ ew, int* __restrict__ pos,
                        unsigned* __restrict__ pairs) {
    int e = blockIdx.x * 256 + threadIdx.x;
    if (e < NE) {
        int p = atomicAdd(&pos[dst[e]], 1);
        unsigned short wh = __builtin_bit_cast(unsigned short, (_Float16)ew[e]);
        pairs[p] = ((unsigned)wh << 16) | (unsigned)srcv[e];
    }
}

// ---------- gather aggregation: one wave per node, 4 edge-groups x 16 lanes ----------
// group g handles edges beg+g, beg+g+4, ...; lane slice = 8 bf16 features (16B).
// final cross-group reduce via shfl_xor(16), shfl_xor(32).
__global__ __launch_bounds__(256) void aggregate_k(const unsigned* __restrict__ pairs,
                                                   const int* __restrict__ ptr,
                                                   unsigned short* __restrict__ hb) {
    int n = blockIdx.x * 4 + (threadIdx.x >> 6);
    int lane = threadIdx.x & 63;
    int grp = lane >> 4, fl = lane & 15;
    int beg = ptr[n], end = ptr[n + 1];
    float acc[8] = {0.f, 0.f, 0.f, 0.f, 0.f, 0.f, 0.f, 0.f};
    float ws = 0.f;
    #pragma unroll 2
    for (int e = beg + grp; e < end; e += 4) {
        unsigned u = pairs[e];
        int s = u & 0xFFFF;
        float w = (float)__builtin_bit_cast(_Float16, (unsigned short)(u >> 16));
        ws += w;
        short8 v = *reinterpret_cast<const short8*>(hb + (size_t)s * 256 + fl * 8);
        #pragma unroll
        for (int i = 0; i < 8; ++i)
            acc[i] += w * b2f((unsigned short)v[i]);
    }
    #pragma unroll
    for (int i = 0; i < 8; ++i) {
        acc[i] += __shfl_xor(acc[i], 16);
        acc[i] += __shfl_xor(acc[i], 32);
    }
    ws += __shfl_xor(ws, 16);
    ws += __shfl_xor(ws, 32);
    if (grp == 0) {
        float inv = 1.f / fmaxf(ws, 1e-8f);
        short8 o;
        #pragma unroll
        for (int i = 0; i < 8; ++i) o[i] = (short)rneb(acc[i] * inv);
        *reinterpret_cast<short8*>(hb + (size_t)n * 256 + 128 + fl * 8) = o;
    }
}

// ---------- MFMA GEMM, zero-LDS: out = hb @ Wb^T + b ----------
__global__ __launch_bounds__(256) void gemm_mfma_k(const unsigned short* __restrict__ hb,
                                                   const unsigned short* __restrict__ Wb,
                                                   const float* __restrict__ b,
                                                   float* __restrict__ out) {
    int w = threadIdx.x >> 6, l = threadIdx.x & 63;
    int l15 = l & 15, lg = l >> 4;
    int rb = blockIdx.x * 128 + w * 32;

    f32x4 acc[2][8];
    #pragma unroll
    for (int i = 0; i < 2; ++i)
        #pragma unroll
        for (int c = 0; c < 8; ++c) acc[i][c] = (f32x4)0.f;

    float bias[8];
    #pragma unroll
    for (int c = 0; c < 8; ++c) bias[c] = b[c * 16 + l15];

    int r0 = rb + l15;      if (r0 > NN - 1) r0 = NN - 1;
    int r1 = rb + 16 + l15; if (r1 > NN - 1) r1 = NN - 1;

    #pragma unroll
    for (int step = 0; step < 8; ++step) {
        int kg = step * 32 + lg * 8;
        short8 a0 = *reinterpret_cast<const short8*>(hb + (size_t)r0 * 256 + kg);
        short8 a1 = *reinterpret_cast<const short8*>(hb + (size_t)r1 * 256 + kg);
        #pragma unroll
        for (int c = 0; c < 8; ++c) {
            short8 bf = *reinterpret_cast<const short8*>(Wb + (size_t)(c * 16 + l15) * 256 + kg);
            acc[0][c] = __builtin_amdgcn_mfma_f32_16x16x32_bf16(a0, bf, acc[0][c], 0, 0, 0);
            acc[1][c] = __builtin_amdgcn_mfma_f32_16x16x32_bf16(a1, bf, acc[1][c], 0, 0, 0);
        }
    }

    #pragma unroll
    for (int i = 0; i < 2; ++i) {
        int rbase = rb + i * 16 + lg * 4;
        #pragma unroll
        for (int c = 0; c < 8; ++c) {
            #pragma unroll
            for (int r = 0; r < 4; ++r) {
                int row = rbase + r;
                if (row < NN)
                    out[(size_t)row * 128 + c * 16 + l15] = acc[i][c][r] + bias[c];
            }
        }
    }
}

// ==================== fallback path (small ws): atomic scatter + f32 GEMM ====================

__global__ void wsum_k(const int* __restrict__ dst, const float* __restrict__ ew,
                       float* __restrict__ wsum) {
    int e = blockIdx.x * 256 + threadIdx.x;
    if (e < NE) atomicAdd(&wsum[dst[e]], ew[e]);
}

__global__ void scatter_k(const int* __restrict__ src, const int* __restrict__ dst,
                          const float* __restrict__ ew, const float* __restrict__ wsum,
                          const float* __restrict__ x, float* __restrict__ agg) {
    int tid = blockIdx.x * 256 + threadIdx.x;
    int e = tid >> 5;
    int p = tid & 31;
    if (e >= NE) return;
    int s = src[e], dn = dst[e];
    float wn = ew[e] / fmaxf(wsum[dn], 1e-8f);
    float4 v = *reinterpret_cast<const float4*>(x + (size_t)s * DIM + p * 4);
    float* o = agg + (size_t)dn * DIM + p * 4;
    atomicAdd(o + 0, wn * v.x);
    atomicAdd(o + 1, wn * v.y);
    atomicAdd(o + 2, wn * v.z);
    atomicAdd(o + 3, wn * v.w);
}

__global__ __launch_bounds__(256) void gemm_f32_k(const float* __restrict__ x,
                                                  const float* __restrict__ agg,
                                                  const float* __restrict__ W,
                                                  const float* __restrict__ b,
                                                  float* __restrict__ out) {
    __shared__ float4 Wl[128 * 64];
    __shared__ float4 hl[16 * 64];
    int t = threadIdx.x;
    int base = blockIdx.x * 80;
    const float4* Wg = reinterpret_cast<const float4*>(W);
    #pragma unroll
    for (int i = 0; i < 32; ++i) {
        int f = t + i * 256;
        int r = f >> 6, kk = f & 63;
        Wl[r * 64 + (kk ^ (r & 7))] = Wg[f];
    }
    int jj = t & 63, wsl = t >> 6, sw = jj & 7;
    float bv[2] = { b[jj], b[jj + 64] };
    const float4* xg = reinterpret_cast<const float4*>(x);
    const float4* ag = reinterpret_cast<const float4*>(agg);
    for (int g = 0; g < 5; ++g) {
        int nbase = base + g * 16;
        __syncthreads();
        #pragma unroll
        for (int i = 0; i < 4; ++i) {
            int f = t + i * 256;
            int ln = f >> 6, kk = f & 63;
            size_t node = (size_t)(nbase + ln);
            hl[ln * 64 + kk] = (kk < 32) ? xg[node * 32 + kk] : ag[node * 32 + (kk - 32)];
        }
        __syncthreads();
        float acc[2][4];
        #pragma unroll
        for (int q = 0; q < 2; ++q)
            #pragma unroll
            for (int n = 0; n < 4; ++n) acc[q][n] = 0.f;
        #pragma unroll 4
        for (int kk = 0; kk < 64; ++kk) {
            float4 h[4];
            #pragma unroll
            for (int n = 0; n < 4; ++n) h[n] = hl[(wsl + 4 * n) * 64 + kk];
            #pragma unroll
            for (int q = 0; q < 2; ++q) {
                float4 wv = Wl[(jj + q * 64) * 64 + (kk ^ sw)];
                #pragma unroll
                for (int n = 0; n < 4; ++n)
                    acc[q][n] += wv.x * h[n].x + wv.y * h[n].y + wv.z * h[n].z + wv.w * h[n].w;
            }
        }
        #pragma unroll
        for (int q = 0; q < 2; ++q)
            #pragma unroll
            for (int n = 0; n < 4; ++n)
                out[(size_t)(nbase + wsl + 4 * n) * 128 + jj + q * 64] = acc[q][n] + bv[q];
    }
}

extern "C" void kernel_launch(void* const* d_in, const int* in_sizes, int n_in,
                              void* d_out, int out_size, void* d_ws, size_t ws_size,
                              hipStream_t stream) {
    const float* x  = (const float*)d_in[0];
    const int*   ei = (const int*)d_in[1];
    const float* ew = (const float*)d_in[2];
    const float* W  = (const float*)d_in[3];
    const float* b  = (const float*)d_in[4];
    float* out = (float*)d_out;
    const int* src = ei;
    const int* dst = ei + NE;

    // ws layout (bytes):
    //   0        : pos/cnt [40000 int] (160000) -- dead after order_k, reused for Wb (64 KB)
    //   163840   : ptr [40001 int]
    //   327680   : bsum [40 int]
    //   328192   : boff [40 int]
    //   331776   : pairs [640000 u32] (2.56 MB)
    //   2893824  : hb [40000][256] bf16 (20.48 MB)
    const size_t off_ptr   = 163840;
    const size_t off_bsum  = 327680;
    const size_t off_boff  = 328192;
    const size_t off_pairs = 331776;
    const size_t off_hb    = 2893824;
    const size_t need = off_hb + (size_t)NN * 256 * 2;

    if (ws_size >= need) {
        int* pos        = (int*)d_ws;
        int* ptr        = (int*)((char*)d_ws + off_ptr);
        int* bsum       = (int*)((char*)d_ws + off_bsum);
        int* boff       = (int*)((char*)d_ws + off_boff);
        unsigned* pairs = (unsigned*)((char*)d_ws + off_pairs);
        unsigned short* hb = (unsigned short*)((char*)d_ws + off_hb);
        unsigned short* Wb = (unsigned short*)d_ws;          // overlays pos after order_k

        hipMemsetAsync(pos, 0, NN * 4, stream);
        prep_k <<<7500, 256, 0, stream>>>(x, hb, dst, pos);
        bsum_k <<<40, 256, 0, stream>>>(pos, bsum);
        scan2_k<<<1, 64, 0, stream>>>(bsum, boff, ptr);
        scan3_k<<<40, 1024, 0, stream>>>(boff, pos, ptr);
        order_k<<<(NE + 255) / 256, 256, 0, stream>>>(dst, src, ew, pos, pairs);
        cvtw_k <<<32, 256, 0, stream>>>(W, Wb);
        aggregate_k<<<NN / 4, 256, 0, stream>>>(pairs, ptr, hb);
        gemm_mfma_k<<<(NN + 127) / 128, 256, 0, stream>>>(hb, Wb, b, out);
    } else {
        float* wsum = (float*)d_ws;
        float* agg  = out;
        hipMemsetAsync(wsum, 0, NN * 4, stream);
        hipMemsetAsync(agg, 0, (size_t)NN * DIM * 4, stream);
        wsum_k   <<<(NE + 255) / 256, 256, 0, stream>>>(dst, ew, wsum);
        scatter_k<<<NE * 32 / 256, 256, 0, stream>>>(src, dst, ew, wsum, x, agg);
        gemm_f32_k<<<500, 256, 0, stream>>>(x, agg, W, b, out);
    }
}